// Round 6
// baseline (86.183 us; speedup 1.0000x reference)
//
#include <hip/hip_runtime.h>

#define Bn 4
#define Dd 128
#define Hh 192
#define Ww 192

#define PLANE (Hh * Ww)           // 36864
#define VOL   (Dd * PLANE)
#define N2D   (Bn * PLANE)
#define WARP_OFF ((size_t)N2D)
#define Y_OFF (WARP_OFF + (size_t)Bn * VOL)

// tile geometry
#define DT 8
#define HT 8
#define WT 16
#define NDB (Dd / DT)    // 16
#define NHB (Hh / HT)    // 24
#define NWB (Ww / WT)    // 12
#define NBLK (Bn * NDB * NHB * NWB)   // 18432
#define NCH (NDB * 2)    // 32 partial chunks per b

// LDS box
#define SZ 16
#define SY 16
#define SXP 40           // floats per row; 40 % 32 == 8 -> 2-way max on reads
#define SXQ 10           // float4 per row
#define STAGE_IT ((SZ * SY * SXQ) / 256)   // 10

typedef float f2 __attribute__((ext_vector_type(2)));
typedef f2 __attribute__((aligned(4))) f2u;
__device__ __forceinline__ f2 load2(const float* p) { return *(const f2u*)p; }

// ---------------- Kernel A: per-batch affine matrices ----------------
__global__ void mats_kernel(const float* __restrict__ rot0,
                            const float* __restrict__ rot1,
                            const float* __restrict__ rot2,
                            const float* __restrict__ tr1,
                            const float* __restrict__ tr2,
                            const float* __restrict__ cp,
                            float* __restrict__ mats) {
    int b = threadIdx.x;
    if (b >= Bn) return;
    float z = rot0[b], y = rot1[b], x = rot2[b];
    float cz = cosf(z), sz = sinf(z);
    float cy = cosf(y), sy = sinf(y);
    float cx = cosf(x), sx = sinf(x);
    float R00 = cz * cy;
    float R01 = -sz * cx + cz * sy * sx;
    float R02 = sz * sx + cz * sy * cx;
    float R10 = sz * cy;
    float R11 = cz * cx + sz * sy * sx;
    float R12 = -cz * sx + sz * sy * cx;
    float R20 = -sy;
    float R21 = cy * sx;
    float R22 = cy * cx;
    float c0 = cp[b * 3 + 0], c1 = cp[b * 3 + 1], c2 = cp[b * 3 + 2];
    float ty = tr1[b] * (float)Hh;
    float tx = tr2[b] * (float)Ww;
    float m03 = -(R00 * c0 + R01 * c1 + R02 * c2) + c0;
    float m13 = -(R10 * c0 + R11 * c1 + R12 * c2) + ty + c1;
    float m23 = -(R20 * c0 + R21 * c1 + R22 * c2) + tx + c2;
    float* M = mats + b * 12;
    M[0] = R00; M[1]  = R01; M[2]  = R02; M[3]  = m03;
    M[4] = R10; M[5]  = R11; M[6]  = R12; M[7]  = m13;
    M[8] = R20; M[9]  = R21; M[10] = R22; M[11] = m23;
}

// ---------------- Kernel B: LDS-tiled warp ----------------
template <bool WP>
__global__ __launch_bounds__(256) void warp_tiled(const float* __restrict__ x,
                                                  const float* __restrict__ mats,
                                                  float* __restrict__ out,
                                                  float* __restrict__ partial) {
    __shared__ __align__(16) float box[SZ * SY * SXP];   // 40960 B

    // ---- XCD-aware block decode ----
    const int g   = blockIdx.x;
    const int xcd = g & 7;
    const int wl  = xcd * (NBLK / 8) + (g >> 3);
    const int wblk = wl % NWB;
    const int t1   = wl / NWB;
    const int hblk = t1 % NHB;
    const int t2   = t1 / NHB;
    const int dblk = t2 & (NDB - 1);
    const int b    = t2 >> 4;

    const int d0 = dblk * DT, h0 = hblk * HT, w0 = wblk * WT;

    const int t    = threadIdx.x;
    const int w_in = t & 15;
    const int h_in = (t >> 4) & 7;
    const int dq   = t >> 7;          // 0/1 -> d half

    const float* M = mats + b * 12;
    const float A0 = M[0], B0 = M[1], C0 = M[2], E0 = M[3];
    const float A1 = M[4], B1 = M[5], C1 = M[6], E1 = M[7];
    const float A2 = M[8], B2 = M[9], C2 = M[10], E2 = M[11];

    // ---- source bounding box over the 8 tile corners ----
    const float dlo = (float)d0, dhi = (float)(d0 + DT - 1);
    const float hlo = (float)h0, hhi = (float)(h0 + HT - 1);
    const float wlo = (float)w0, whi = (float)(w0 + WT - 1);

    const float loZ = E0 + fminf(A0 * dlo, A0 * dhi) + fminf(B0 * hlo, B0 * hhi) + fminf(C0 * wlo, C0 * whi);
    const float hiZ = E0 + fmaxf(A0 * dlo, A0 * dhi) + fmaxf(B0 * hlo, B0 * hhi) + fmaxf(C0 * wlo, C0 * whi);
    const float loY = E1 + fminf(A1 * dlo, A1 * dhi) + fminf(B1 * hlo, B1 * hhi) + fminf(C1 * wlo, C1 * whi);
    const float hiY = E1 + fmaxf(A1 * dlo, A1 * dhi) + fmaxf(B1 * hlo, B1 * hhi) + fmaxf(C1 * wlo, C1 * whi);
    const float loX = E2 + fminf(A2 * dlo, A2 * dhi) + fminf(B2 * hlo, B2 * hhi) + fminf(C2 * wlo, C2 * whi);
    const float hiX = E2 + fmaxf(A2 * dlo, A2 * dhi) + fmaxf(B2 * hlo, B2 * hhi) + fmaxf(C2 * wlo, C2 * whi);

    // +/-1 cell slack so corner-bound float rounding can never go out of box
    const int lz = max(0, (int)floorf(loZ) - 1);
    const int hz = min(Dd - 1, (int)floorf(hiZ) + 2);
    const int ly = max(0, (int)floorf(loY) - 1);
    const int hy = min(Hh - 1, (int)floorf(hiY) + 2);
    const int lx = max(0, (int)floorf(loX) - 1);
    const int lx4 = lx & ~3;
    const int hx = min(Ww - 2, (int)floorf(hiX) + 2);

    const bool fits = (hz - lz <= SZ - 1) && (hy - ly <= SY - 1) && (hx - lx4 <= SXP - 2);
    const bool interior = (loZ >= 0.01f) && (hiZ < (float)(Dd - 1) - 0.01f) &&
                          (loY >= 0.01f) && (hiY < (float)(Hh - 1) - 0.01f) &&
                          (loX >= 0.01f) && (hiX < (float)(Ww - 1) - 0.01f);

    const float* __restrict__ V = x + (size_t)b * VOL;
    float* __restrict__ obase = out + WARP_OFF + (size_t)b * VOL +
                                (size_t)(d0 + dq * 4) * PLANE +
                                (size_t)(h0 + h_in) * Ww + (w0 + w_in);

    const float fh = (float)(h0 + h_in), fw = (float)(w0 + w_in);
    const float hb0 = B0 * fh + C0 * fw + E0;
    const float hb1 = B1 * fh + C1 * fw + E1;
    const float hb2 = B2 * fh + C2 * fw + E2;

    float sum = 0.0f;

    if (fits) {
        // ---- stage the box: q-aligned dwordx4 ----
        const int qbase = lx4 >> 2;
        #pragma unroll
        for (int i = 0; i < STAGE_IT; ++i) {
            const int e  = i * 256 + t;
            const int z  = e / (SY * SXQ);            // /160
            const int r  = e - z * (SY * SXQ);
            const int yy = r / SXQ;                   // /10
            const int qc = r - yy * SXQ;
            const int zz = min(lz + z, Dd - 1);
            const int yv = min(ly + yy, Hh - 1);
            const int qcol = min(qbase + qc, Ww / 4 - 1);
            const float4 v = *(const float4*)(V + (size_t)zz * PLANE + yv * Ww + 4 * qcol);
            *(float4*)&box[(z * SY + yy) * SXP + 4 * qc] = v;
        }
        __syncthreads();

        if (interior) {
            // ---- fast path: no clamps, no masks ----
            const float hb0i = hb0 - (float)lz + A0 * (float)(d0 + dq * 4);
            const float hb1i = hb1 - (float)ly + A1 * (float)(d0 + dq * 4);
            const float hb2i = hb2 - (float)lx4 + A2 * (float)(d0 + dq * 4);
            #pragma unroll
            for (int j = 0; j < 4; ++j) {
                const float fd = (float)j;
                const float gz = fmaf(A0, fd, hb0i);
                const float gy = fmaf(A1, fd, hb1i);
                const float gx = fmaf(A2, fd, hb2i);
                const float fz = floorf(gz), fy = floorf(gy), fx = floorf(gx);
                const float tz = gz - fz, ty = gy - fy, tx = gx - fx;
                const int izr = (int)fz, iyr = (int)fy, ixr = (int)fx;
                const int base = (izr * SY + iyr) * SXP + ixr;

                const float q00l = box[base],                 q00h = box[base + 1];
                const float q01l = box[base + SXP],           q01h = box[base + SXP + 1];
                const float q10l = box[base + SY * SXP],      q10h = box[base + SY * SXP + 1];
                const float q11l = box[base + SY * SXP + SXP], q11h = box[base + SY * SXP + SXP + 1];

                const float wx0 = 1.0f - tx, wy0 = 1.0f - ty, wz0 = 1.0f - tz;
                const float v00 = fmaf(wx0, q00l, tx * q00h);
                const float v01 = fmaf(wx0, q01l, tx * q01h);
                const float v10 = fmaf(wx0, q10l, tx * q10h);
                const float v11 = fmaf(wx0, q11l, tx * q11h);
                const float vz0 = fmaf(wy0, v00, ty * v01);
                const float vz1 = fmaf(wy0, v10, ty * v11);
                const float val = fmaf(wz0, vz0, tz * vz1);

                __builtin_nontemporal_store(val, obase + (size_t)j * PLANE);
                sum += val;
            }
        } else {
            // ---- masked LDS path (boundary tiles) ----
            #pragma unroll
            for (int j = 0; j < 4; ++j) {
                const float fd = (float)(d0 + dq * 4 + j);
                const float gz = fmaf(A0, fd, hb0);
                const float gy = fmaf(A1, fd, hb1);
                const float gx = fmaf(A2, fd, hb2);

                const float fz = floorf(gz), fy = floorf(gy), fx = floorf(gx);
                const float tz = gz - fz, ty = gy - fy, tx = gx - fx;
                const int iz = (int)fz, iy = (int)fy, ix = (int)fx;

                const float wz0 = ((unsigned)iz       < (unsigned)Dd) ? (1.0f - tz) : 0.0f;
                const float wz1 = ((unsigned)(iz + 1) < (unsigned)Dd) ? tz : 0.0f;
                const float wy0 = ((unsigned)iy       < (unsigned)Hh) ? (1.0f - ty) : 0.0f;
                const float wy1 = ((unsigned)(iy + 1) < (unsigned)Hh) ? ty : 0.0f;
                const float wx0 = ((unsigned)ix       < (unsigned)Ww) ? (1.0f - tx) : 0.0f;
                const float wx1 = ((unsigned)(ix + 1) < (unsigned)Ww) ? tx : 0.0f;

                const bool right  = (ix >= Ww - 1);
                const bool leftok = (ix >= 0);
                const float WL = (right ? 0.0f : wx0) + (leftok ? 0.0f : wx1);
                const float WH = (right ? wx0 : 0.0f) + (leftok ? wx1 : 0.0f);

                const int zc0 = min(max(iz, 0), Dd - 1) - lz;
                const int zc1 = min(max(iz + 1, 0), Dd - 1) - lz;
                const int yc0 = min(max(iy, 0), Hh - 1) - ly;
                const int yc1 = min(max(iy + 1, 0), Hh - 1) - ly;
                const int ixl = min(max(ix, 0), Ww - 2);
                const int col = max(ixl - lx4, 0);

                const int b00 = (zc0 * SY + yc0) * SXP + col;
                const int b01 = (zc0 * SY + yc1) * SXP + col;
                const int b10 = (zc1 * SY + yc0) * SXP + col;
                const int b11 = (zc1 * SY + yc1) * SXP + col;

                const float v00 = fmaf(WL, box[b00], WH * box[b00 + 1]);
                const float v01 = fmaf(WL, box[b01], WH * box[b01 + 1]);
                const float v10 = fmaf(WL, box[b10], WH * box[b10 + 1]);
                const float v11 = fmaf(WL, box[b11], WH * box[b11 + 1]);

                const float vz0 = fmaf(wy0, v00, wy1 * v01);
                const float vz1 = fmaf(wy0, v10, wy1 * v11);
                const float val = fmaf(wz0, vz0, wz1 * vz1);

                __builtin_nontemporal_store(val, obase + (size_t)j * PLANE);
                sum += val;
            }
        }
    } else {
        // ---- fallback: direct global gather ----
        #pragma unroll
        for (int j = 0; j < 4; ++j) {
            const float fd = (float)(d0 + dq * 4 + j);
            const float gz = fmaf(A0, fd, hb0);
            const float gy = fmaf(A1, fd, hb1);
            const float gx = fmaf(A2, fd, hb2);

            const float fz = floorf(gz), fy = floorf(gy), fx = floorf(gx);
            const float tz = gz - fz, ty = gy - fy, tx = gx - fx;
            const int iz = (int)fz, iy = (int)fy, ix = (int)fx;

            const float wz0 = ((unsigned)iz       < (unsigned)Dd) ? (1.0f - tz) : 0.0f;
            const float wz1 = ((unsigned)(iz + 1) < (unsigned)Dd) ? tz : 0.0f;
            const float wy0 = ((unsigned)iy       < (unsigned)Hh) ? (1.0f - ty) : 0.0f;
            const float wy1 = ((unsigned)(iy + 1) < (unsigned)Hh) ? ty : 0.0f;
            const float wx0 = ((unsigned)ix       < (unsigned)Ww) ? (1.0f - tx) : 0.0f;
            const float wx1 = ((unsigned)(ix + 1) < (unsigned)Ww) ? tx : 0.0f;

            const bool right  = (ix >= Ww - 1);
            const bool leftok = (ix >= 0);
            const float WL = (right ? 0.0f : wx0) + (leftok ? 0.0f : wx1);
            const float WH = (right ? wx0 : 0.0f) + (leftok ? wx1 : 0.0f);

            const int iz0c = min(max(iz, 0), Dd - 1);
            const int iz1c = min(max(iz + 1, 0), Dd - 1);
            const int iy0c = min(max(iy, 0), Hh - 1);
            const int iy1c = min(max(iy + 1, 0), Hh - 1);
            const int ixl  = min(max(ix, 0), Ww - 2);

            const f2 q00 = load2(V + (size_t)iz0c * PLANE + iy0c * Ww + ixl);
            const f2 q01 = load2(V + (size_t)iz0c * PLANE + iy1c * Ww + ixl);
            const f2 q10 = load2(V + (size_t)iz1c * PLANE + iy0c * Ww + ixl);
            const f2 q11 = load2(V + (size_t)iz1c * PLANE + iy1c * Ww + ixl);

            const float v00 = fmaf(WL, q00.x, WH * q00.y);
            const float v01 = fmaf(WL, q01.x, WH * q01.y);
            const float v10 = fmaf(WL, q10.x, WH * q10.y);
            const float v11 = fmaf(WL, q11.x, WH * q11.y);

            const float vz0 = fmaf(wy0, v00, wy1 * v01);
            const float vz1 = fmaf(wy0, v10, wy1 * v11);
            const float val = fmaf(wz0, vz0, wz1 * vz1);

            __builtin_nontemporal_store(val, obase + (size_t)j * PLANE);
            sum += val;
        }
    }

    if (WP) {
        // 32 chunks: [b][dblk*2+dq][h][w] — no cross-thread reduction needed
        const int ch = dblk * 2 + dq;
        __builtin_nontemporal_store(sum,
            partial + ((size_t)(b * NCH + ch) * Hh + (h0 + h_in)) * Ww + (w0 + w_in));
    }
}

// ---------------- Kernel C: reduce partials -> x_2d, copy y -------------
__global__ __launch_bounds__(256) void reduce_kernel(const float* __restrict__ partial,
                                                     const float* __restrict__ yin,
                                                     float* __restrict__ out) {
    const int idx = blockIdx.x * 256 + threadIdx.x;
    if (idx >= N2D) return;
    const int b = idx / PLANE;
    const int rem = idx - b * PLANE;
    const float* p = partial + (size_t)b * NCH * PLANE + rem;
    float s = 0.0f;
    #pragma unroll
    for (int c = 0; c < NCH; ++c) s += p[(size_t)c * PLANE];
    out[idx] = s * (1.0f / (float)Dd);
    out[Y_OFF + idx] = yin[idx];
}

// ---------------- Fallback reduce: read x_warp directly -----------------
__global__ __launch_bounds__(256) void reduce_fallback_kernel(const float* __restrict__ yin,
                                                              float* __restrict__ out) {
    const int idx = blockIdx.x * 256 + threadIdx.x;
    if (idx >= N2D) return;
    const int b = idx / PLANE;
    const int rem = idx - b * PLANE;
    const float* p = out + WARP_OFF + (size_t)b * VOL + rem;
    float s = 0.0f;
    #pragma unroll 8
    for (int d = 0; d < Dd; ++d) s += p[(size_t)d * PLANE];
    out[idx] = s * (1.0f / (float)Dd);
    out[Y_OFF + idx] = yin[idx];
}

extern "C" void kernel_launch(void* const* d_in, const int* in_sizes, int n_in,
                              void* d_out, int out_size, void* d_ws, size_t ws_size,
                              hipStream_t stream) {
    const float* x    = (const float*)d_in[0];
    const float* yin  = (const float*)d_in[1];
    const float* rot0 = (const float*)d_in[2];
    const float* rot1 = (const float*)d_in[3];
    const float* rot2 = (const float*)d_in[4];
    const float* tr1  = (const float*)d_in[5];
    const float* tr2  = (const float*)d_in[6];
    const float* cp   = (const float*)d_in[7];

    float* mats = (float*)d_ws;
    float* partial = (float*)d_ws + 64;
    const size_t need = (64 + (size_t)Bn * NCH * PLANE) * sizeof(float);

    mats_kernel<<<1, 64, 0, stream>>>(rot0, rot1, rot2, tr1, tr2, cp, mats);

    if (ws_size >= need) {
        warp_tiled<true><<<NBLK, 256, 0, stream>>>(x, mats, (float*)d_out, partial);
        reduce_kernel<<<(N2D + 255) / 256, 256, 0, stream>>>(partial, yin, (float*)d_out);
    } else {
        warp_tiled<false><<<NBLK, 256, 0, stream>>>(x, mats, (float*)d_out, partial);
        reduce_fallback_kernel<<<(N2D + 255) / 256, 256, 0, stream>>>(yin, (float*)d_out);
    }
}